// Round 5
// baseline (414.580 us; speedup 1.0000x reference)
//
#include <hip/hip_runtime.h>
#include <hip/hip_bf16.h>

using u16_t = unsigned short;

constexpr int DIMc = 256, Tt = 2048, Kk = 1024, Dd = 64;

// ws: floats [0,1024) = ||c_k||^2 ; ints at byte 4096: flags[0]=dtype(1=fp32),
// flags[1]=w-swap (1 = first 16384-el array is W_out). Total < 5 KB.

__device__ __forceinline__ float b2f(u16_t v) {
  return __uint_as_float(((unsigned)v) << 16);
}
template<int FP32>
__device__ __forceinline__ float ldv(const void* p, size_t i) {
  if (FP32) return ((const float*)p)[i];
  return b2f(((const u16_t*)p)[i]);
}

// One block. Decides input dtype and which 16384-el array is W_in.
__global__ void nsvq_detect(const void* in, const void* w0, int* flags) {
  __shared__ int sb[256], sz[256];
  __shared__ float sf[256];
  const u16_t* p = (const u16_t*)in;
  int bad = 0, zev = 0;
  for (int i = threadIdx.x; i < 65536; i += 256) {
    int e = (p[i] >> 7) & 0xFF;              // bf16-exponent view of this 16-bit half
    bad += (e >= 140);                       // |v|>=2^13: impossible for N(0,1) bf16
    zev += (((i & 1) == 0) && (p[i] == 0));  // zero low-half (bf16-rounded fp32 storage)
  }
  sb[threadIdx.x] = bad; sz[threadIdx.x] = zev;
  __syncthreads();
  for (int o = 128; o > 0; o >>= 1) {
    if (threadIdx.x < o) { sb[threadIdx.x] += sb[threadIdx.x+o]; sz[threadIdx.x] += sz[threadIdx.x+o]; }
    __syncthreads();
  }
  const int fp32 = (sb[0] > 655) || (sz[0] > 16384);
  float ss = 0.f;  // sum-sq of candidate w0: W_in -> ~64, W_out -> ~256
  if (fp32) { const float* q = (const float*)w0;
    for (int i = threadIdx.x; i < 16384; i += 256) { float v = q[i]; ss = fmaf(v, v, ss); } }
  else      { const u16_t* q = (const u16_t*)w0;
    for (int i = threadIdx.x; i < 16384; i += 256) { float v = b2f(q[i]); ss = fmaf(v, v, ss); } }
  sf[threadIdx.x] = ss;
  __syncthreads();
  for (int o = 128; o > 0; o >>= 1) {
    if (threadIdx.x < o) sf[threadIdx.x] += sf[threadIdx.x+o];
    __syncthreads();
  }
  if (threadIdx.x == 0) { flags[0] = fp32; flags[1] = (sf[0] > 128.f) ? 1 : 0; }
}

template<int FP32>
__global__ void nsvq_prep(const void* cb, const int* __restrict__ flags,
                          float* __restrict__ cnorm) {
  if (flags[0] != FP32) return;
  int k = blockIdx.x * 256 + threadIdx.x;   // 4 blocks -> k in [0,1024)
  float s = 0.f;
  #pragma unroll
  for (int d = 0; d < Dd; ++d) { float v = ldv<FP32>(cb, (size_t)k * Dd + d); s = fmaf(v, v, s); }
  cnorm[k] = s;
}

// One block = one (b, 64-t tile). 8 waves; lane = t index. OUTPUT IS FP32.
template<int FP32>
__global__ __launch_bounds__(512) void nsvq_main(
    const void* in, const void* rnd, const void* cb,
    const void* w0, const void* w1, const void* bin, const void* bout,
    const int* __restrict__ flags, const float* __restrict__ cnorm,
    float* __restrict__ out) {
  if (flags[0] != FP32) return;            // uniform early exit before any barrier
  const void* Win  = flags[1] ? w1 : w0;   // uniform select (variance-detected)
  const void* Wout = flags[1] ? w0 : w1;

  const int tid = threadIdx.x;
  const int l = tid & 63;
  const int w = __builtin_amdgcn_readfirstlane(tid >> 6);  // wave id 0..7
  const int blk = blockIdx.x;                               // 512 blocks
  const int b  = blk >> 5;
  const int t0 = (blk & 31) << 6;

  __shared__ float xs[Dd][64];    // x tile [d][t]
  __shared__ float xnp[8][64];    // ||x||^2 partials
  __shared__ float rnp[8][64];    // ||rand||^2 partials
  __shared__ float mnp[8][64];    // per-wave min(cnorm - 2 x.c)
  __shared__ float scl[64];       // final scale per t

  // ---- phase 1: encode. wave w computes d in [w*8, w*8+8) for all 256 c ----
  const int dbase = w * 8;
  float acc[8];
  #pragma unroll
  for (int j = 0; j < 8; ++j) acc[j] = ldv<FP32>(bin, dbase + j);
  const size_t in_base = (size_t)b * DIMc * Tt + t0 + l;
  #pragma unroll 4
  for (int c = 0; c < DIMc; ++c) {
    float v = ldv<FP32>(in, in_base + (size_t)c * Tt);      // coalesced across lanes
    #pragma unroll
    for (int j = 0; j < 8; ++j)
      acc[j] = fmaf(v, ldv<FP32>(Win, c * Dd + dbase + j), acc[j]); // uniform -> scalar
  }
  float xn = 0.f;
  #pragma unroll
  for (int j = 0; j < 8; ++j) { xs[dbase + j][l] = acc[j]; xn = fmaf(acc[j], acc[j], xn); }
  xnp[w][l] = xn;

  const size_t r_base = (size_t)(b * Tt + t0 + l) * Dd;
  float rn = 0.f;
  #pragma unroll
  for (int j = 0; j < 8; ++j) {
    float v = ldv<FP32>(rnd, r_base + dbase + j);
    rn = fmaf(v, v, rn);
  }
  rnp[w][l] = rn;
  __syncthreads();

  // ---- phase 2: distances. wave w covers k in [w*128, w*128+128) ----
  float xv[64];
  #pragma unroll
  for (int d = 0; d < Dd; ++d) xv[d] = xs[d][l];   // stride-1 lanes: conflict-free
  float mv = 3.4e38f;
  const int k0 = w * 128;
  for (int k = k0; k < k0 + 128; ++k) {
    float s = 0.f;
    #pragma unroll
    for (int d = 0; d < Dd; ++d)
      s = fmaf(xv[d], ldv<FP32>(cb, (size_t)k * Dd + d), s);  // uniform -> scalar
    mv = fminf(mv, fmaf(-2.f, s, cnorm[k]));
  }
  mnp[w][l] = mv;
  __syncthreads();

  // ---- phase 3: scale per t (wave 0) ----
  if (w == 0) {
    float x2 = 0.f, r2 = 0.f, m = 3.4e38f;
    #pragma unroll
    for (int j = 0; j < 8; ++j) { x2 += xnp[j][l]; r2 += rnp[j][l]; m = fminf(m, mnp[j][l]); }
    float resid2 = fmaxf(x2 + m, 0.f);             // ||x - hard||^2
    scl[l] = sqrtf(resid2) / (sqrtf(r2) + 1e-12f);
  }
  __syncthreads();

  // ---- phase 4: q = x + scale*rand ; decode. wave w covers c in [w*32, w*32+32) ----
  const float sc = scl[l];
  #pragma unroll
  for (int d = 0; d < Dd; ++d) xv[d] = fmaf(sc, ldv<FP32>(rnd, r_base + d), xv[d]);
  float* outb = out + (size_t)b * DIMc * Tt + t0 + l;
  const int c0 = w * 32;
  for (int c = c0; c < c0 + 32; ++c) {
    float o = ldv<FP32>(bout, c);
    #pragma unroll
    for (int d = 0; d < Dd; ++d)
      o = fmaf(xv[d], ldv<FP32>(Wout, (size_t)d * DIMc + c), o);  // uniform column
    outb[(size_t)c * Tt] = o;                      // coalesced FP32 store
  }
}

extern "C" void kernel_launch(void* const* d_in, const int* in_sizes, int n_in,
                              void* d_out, int out_size, void* d_ws, size_t ws_size,
                              hipStream_t stream) {
  // Resolve pointers BY ELEMENT COUNT (robust to ordering assumptions).
  const void *in = nullptr, *cb = nullptr, *rnd = nullptr, *bin = nullptr, *bout = nullptr;
  const void* w16[2] = {nullptr, nullptr}; int nw = 0;
  for (int i = 0; i < n_in; ++i) {
    switch (in_sizes[i]) {
      case 8388608: in  = d_in[i]; break;
      case 65536:   cb  = d_in[i]; break;
      case 2097152: rnd = d_in[i]; break;
      case 64:      bin = d_in[i]; break;
      case 256:     bout= d_in[i]; break;
      case 16384:   if (nw < 2) w16[nw++] = d_in[i]; break;
      default: break;
    }
  }
  if (!in)  in  = d_in[0];
  if (!cb)  cb  = d_in[1];
  if (nw < 2) { w16[0] = d_in[2]; w16[1] = d_in[4]; }
  if (!bin) bin = d_in[3];
  if (!bout) bout = d_in[5];
  if (!rnd) rnd = d_in[6];

  float* cnorm = (float*)d_ws;
  int*   flags = (int*)((char*)d_ws + 4096);
  float* outp  = (float*)d_out;

  nsvq_detect<<<1, 256, 0, stream>>>(in, w16[0], flags);
  nsvq_prep<0><<<4, 256, 0, stream>>>(cb, flags, cnorm);
  nsvq_prep<1><<<4, 256, 0, stream>>>(cb, flags, cnorm);
  nsvq_main<0><<<512, 512, 0, stream>>>(in, rnd, cb, w16[0], w16[1], bin, bout, flags, cnorm, outp);
  nsvq_main<1><<<512, 512, 0, stream>>>(in, rnd, cb, w16[0], w16[1], bin, bout, flags, cnorm, outp);
}

// Round 6
// 138.896 us; speedup vs baseline: 2.9848x; 2.9848x over previous
//
#include <hip/hip_runtime.h>
#include <hip/hip_bf16.h>

typedef __bf16 bf16x8 __attribute__((ext_vector_type(8)));
typedef unsigned short u16x8 __attribute__((ext_vector_type(8)));
typedef unsigned short u16x4 __attribute__((ext_vector_type(4)));
typedef float f32x4 __attribute__((ext_vector_type(4)));

constexpr int DIMc = 256, Tt = 2048, Kk = 1024, Dd = 64;

__device__ __forceinline__ unsigned short f2b(float f) {  // RNE float->bf16 bits
  unsigned u = __float_as_uint(f);
  return (unsigned short)((u + 0x7FFFu + ((u >> 16) & 1u)) >> 16);
}
__device__ __forceinline__ float b2f(unsigned short v) {
  return __uint_as_float(((unsigned)v) << 16);
}
__device__ __forceinline__ f32x4 mfma16(u16x8 a, u16x8 b, f32x4 c) {
  return __builtin_amdgcn_mfma_f32_16x16x32_bf16(
      __builtin_bit_cast(bf16x8, a), __builtin_bit_cast(bf16x8, b), c, 0, 0, 0);
}
// XOR-swizzled index into [r][256] u16 (512B rows): 16B blocks permuted by row.
__device__ __forceinline__ int ix256(int r, int c) {
  return r * 256 + ((((c >> 3) ^ (r & 7)) << 3) | (c & 7));
}
// XOR-swizzled index into [r][64] u16 (128B rows).
__device__ __forceinline__ int ix64(int r, int c) {
  return r * 64 + ((((c >> 3) ^ (r & 7)) << 3) | (c & 7));
}

__global__ void nsvq_prep(const float* __restrict__ cb, float* __restrict__ cnorm) {
  int k = blockIdx.x * 256 + threadIdx.x;   // 4 blocks -> k in [0,1024)
  float s = 0.f;
  #pragma unroll
  for (int d = 0; d < Dd; ++d) { float v = cb[(size_t)k * Dd + d]; s = fmaf(v, v, s); }
  cnorm[k] = s;
}

// Block = 64 tokens (one b, t0..t0+63). 4 waves; wave w owns n-tile w (16 tokens).
__global__ __launch_bounds__(256, 2) void nsvq_mfma(
    const float* __restrict__ in, const float* __restrict__ rnd,
    const float* __restrict__ cb, const float* __restrict__ Win,
    const float* __restrict__ bin, const float* __restrict__ Wout,
    const float* __restrict__ bout, const float* __restrict__ cnorm,
    float* __restrict__ out) {
  __shared__ unsigned short regA[64 * 256];  // WtIn[d][c] ; later Cb chunk [128][64]
  __shared__ unsigned short regB[64 * 256];  // InT[t][c]  ; later WoT[c][d] (256x64)
  __shared__ unsigned short Xt[64 * 64];     // x / q tile, [t][d] bf16 (swizzled)
  __shared__ float cnS[128];
  __shared__ float rr2S[64];
  __shared__ float binS[64];
  __shared__ float boutS[256];

  const int tid  = threadIdx.x;
  const int lane = tid & 63;
  const int w    = tid >> 6;        // wave id 0..3
  const int quad = lane >> 4;
  const int col  = lane & 15;
  const int b  = blockIdx.x >> 5;
  const int t0 = (blockIdx.x & 31) << 6;

  // ---- stage: WtIn[d][c] = W_in[c][d] (bf16), InT[t][c] = in[b][c][t0+t] ----
  for (int i = tid; i < 16384; i += 256) {
    int c = i >> 6, d = i & 63;                       // consecutive i -> consecutive d
    regA[ix256(d, c)] = f2b(Win[i]);                  // Win[c*64+d]
  }
  const float* inb = in + (size_t)b * DIMc * Tt + t0;
  for (int c = (tid >> 6); c < DIMc; c += 4) {
    regB[ix256(lane, c)] = f2b(inb[(size_t)c * Tt + lane]);  // coalesced in t
  }
  if (tid < 64)  binS[tid]  = bin[tid];
  if (tid < 256) boutS[tid] = bout[tid];

  // ---- rr2 per token (wave w: tokens w*16..w*16+15); cache rnd in regs ----
  const float* rb = rnd + (size_t)(b * Tt + t0) * Dd;
  float rv[16];
  #pragma unroll
  for (int tt = 0; tt < 16; ++tt) {
    float v = rb[(size_t)(w * 16 + tt) * Dd + lane];  // 256B coalesced per wave
    rv[tt] = v;
    float s = v * v;
    s += __shfl_xor(s, 1);  s += __shfl_xor(s, 2);  s += __shfl_xor(s, 4);
    s += __shfl_xor(s, 8);  s += __shfl_xor(s, 16); s += __shfl_xor(s, 32);
    if (lane == 0) rr2S[w * 16 + tt] = s;
  }
  __syncthreads();

  // ---- encode: X^T[d][t] = W_in^T · In ; M=64, N=16 (this wave), K=256 ----
  u16x8 Bf[8];
  #pragma unroll
  for (int kt = 0; kt < 8; ++kt)
    Bf[kt] = *(const u16x8*)(regB + ix256(w * 16 + col, kt * 32 + quad * 8));
  f32x4 acc[4];
  #pragma unroll
  for (int mt = 0; mt < 4; ++mt) {
    #pragma unroll
    for (int r = 0; r < 4; ++r) acc[mt][r] = binS[mt * 16 + quad * 4 + r];
    #pragma unroll
    for (int kt = 0; kt < 8; ++kt) {
      u16x8 Af = *(const u16x8*)(regA + ix256(mt * 16 + col, kt * 32 + quad * 8));
      acc[mt] = mfma16(Af, Bf[kt], acc[mt]);
    }
  }
  // x^2 per token (fp32 accs) + write Xt as bf16
  float x2v = 0.f;
  #pragma unroll
  for (int mt = 0; mt < 4; ++mt) {
    u16x4 pk;
    #pragma unroll
    for (int r = 0; r < 4; ++r) {
      x2v = fmaf(acc[mt][r], acc[mt][r], x2v);
      pk[r] = f2b(acc[mt][r]);
    }
    *(u16x4*)(Xt + ix64(w * 16 + col, mt * 16 + quad * 4)) = pk;  // 8B write
  }
  x2v += __shfl_xor(x2v, 16);
  x2v += __shfl_xor(x2v, 32);      // now x2 of token (w*16+col) in every lane
  __syncthreads();                 // Xt ready; regA/regB free

  // ---- stage WoT[c][d] = W_out[d][c] into regB (used in decode) ----
  for (int i = tid; i < 16384; i += 256) {
    int d = i >> 8, c = i & 255;                      // consecutive i -> consecutive c
    regB[ix64(c, d)] = f2b(Wout[i]);                  // Wout[d*256+c]
  }

  // ---- distances: stream codebook in 8 chunks of 128 codes ----
  u16x8 Xf[2];
  #pragma unroll
  for (int kt = 0; kt < 2; ++kt)
    Xf[kt] = *(const u16x8*)(Xt + ix64(w * 16 + col, kt * 32 + quad * 8));
  float minv = 3.4e38f;
  for (int ch = 0; ch < 8; ++ch) {
    __syncthreads();               // prev chunk's MFMAs (and WoT stores) done
    for (int i = tid; i < 8192; i += 256) {
      int k = i >> 6, d = i & 63;
      regA[ix64(k, d)] = f2b(cb[(size_t)ch * 8192 + i]);
    }
    if (tid < 128) cnS[tid] = cnorm[ch * 128 + tid];
    __syncthreads();
    #pragma unroll
    for (int m = 0; m < 8; ++m) {
      f32x4 a = {0.f, 0.f, 0.f, 0.f};
      u16x8 A0 = *(const u16x8*)(regA + ix64(m * 16 + col, quad * 8));
      u16x8 A1 = *(const u16x8*)(regA + ix64(m * 16 + col, 32 + quad * 8));
      a = mfma16(A0, Xf[0], a);
      a = mfma16(A1, Xf[1], a);
      #pragma unroll
      for (int r = 0; r < 4; ++r)
        minv = fminf(minv, fmaf(-2.f, a[r], cnS[m * 16 + quad * 4 + r]));
    }
  }
  minv = fminf(minv, __shfl_xor(minv, 16));
  minv = fminf(minv, __shfl_xor(minv, 32));  // min over all 1024 codes, token (w*16+col)

  // ---- noise scale, q-update (own-wave Xt rows: no block barrier needed) ----
  float r2  = fmaxf(x2v + minv, 0.f);                 // ||x-hard||^2
  float scv = sqrtf(r2) / (sqrtf(rr2S[w * 16 + col]) + 1e-12f);
  #pragma unroll
  for (int tt = 0; tt < 16; ++tt) {
    float s = __shfl(scv, tt);                        // sc of token w*16+tt
    int idx = ix64(w * 16 + tt, lane);                // lane = d
    Xt[idx] = f2b(fmaf(s, rv[tt], b2f(Xt[idx])));
  }

  // ---- decode: Out[c][t] = W_out^T · q^T ; M=256, N=16, K=64 ----
  u16x8 Qf0 = *(const u16x8*)(Xt + ix64(w * 16 + col, quad * 8));
  u16x8 Qf1 = *(const u16x8*)(Xt + ix64(w * 16 + col, 32 + quad * 8));
  float* ob0 = out + (size_t)b * DIMc * Tt + t0 + w * 16 + col;
  #pragma unroll
  for (int mt = 0; mt < 16; ++mt) {
    f32x4 a;
    #pragma unroll
    for (int r = 0; r < 4; ++r) a[r] = boutS[mt * 16 + quad * 4 + r];
    u16x8 A0 = *(const u16x8*)(regB + ix64(mt * 16 + col, quad * 8));
    u16x8 A1 = *(const u16x8*)(regB + ix64(mt * 16 + col, 32 + quad * 8));
    a = mfma16(A0, Qf0, a);
    a = mfma16(A1, Qf1, a);
    float* ob = ob0 + (size_t)(mt * 16 + quad * 4) * Tt;
    #pragma unroll
    for (int r = 0; r < 4; ++r) ob[(size_t)r * Tt] = a[r];
  }
}

extern "C" void kernel_launch(void* const* d_in, const int* in_sizes, int n_in,
                              void* d_out, int out_size, void* d_ws, size_t ws_size,
                              hipStream_t stream) {
  // Resolve pointers BY ELEMENT COUNT (robust; fp32 confirmed in R5).
  const float *in = nullptr, *cb = nullptr, *rnd = nullptr, *bin = nullptr, *bout = nullptr;
  const float* w16[2] = {nullptr, nullptr}; int nw = 0;
  for (int i = 0; i < n_in; ++i) {
    switch (in_sizes[i]) {
      case 8388608: in  = (const float*)d_in[i]; break;
      case 65536:   cb  = (const float*)d_in[i]; break;
      case 2097152: rnd = (const float*)d_in[i]; break;
      case 64:      bin = (const float*)d_in[i]; break;
      case 256:     bout= (const float*)d_in[i]; break;
      case 16384:   if (nw < 2) w16[nw++] = (const float*)d_in[i]; break;
      default: break;
    }
  }
  if (!in)  in  = (const float*)d_in[0];
  if (!cb)  cb  = (const float*)d_in[1];
  if (nw < 2) { w16[0] = (const float*)d_in[2]; w16[1] = (const float*)d_in[4]; }
  if (!bin) bin = (const float*)d_in[3];
  if (!bout) bout = (const float*)d_in[5];
  if (!rnd) rnd = (const float*)d_in[6];
  const float* Win  = w16[0];   // dict order: W_in comes first
  const float* Wout = w16[1];

  float* cnorm = (float*)d_ws;  // 4 KB
  float* outp  = (float*)d_out;

  nsvq_prep<<<4, 256, 0, stream>>>(cb, cnorm);
  nsvq_mfma<<<512, 256, 0, stream>>>(in, rnd, cb, Win, bin, Wout, bout, cnorm, outp);
}

// Round 7
// 115.964 us; speedup vs baseline: 3.5751x; 1.1977x over previous
//
#include <hip/hip_runtime.h>
#include <hip/hip_bf16.h>

typedef __bf16 bf16x8 __attribute__((ext_vector_type(8)));
typedef unsigned short u16x8 __attribute__((ext_vector_type(8)));
typedef unsigned short u16x4 __attribute__((ext_vector_type(4)));
typedef float f32x4 __attribute__((ext_vector_type(4)));
typedef unsigned short u16;

constexpr int DIMc = 256, Tt = 2048, Kk = 1024, Dd = 64;

// ws layout (u16 offsets): WinT[64][288] @0 ; CbX[1024][96] @18432 ; WoX[256][96] @116736.
// CbX row k = [-2*c_k (64), cn_hi, cn_lo, 0*30]; WoX row c = [Wout[:,c] (64), bout_hi, bout_lo, 0*30];
// WinT row d = [Win[:,d] (256), bin_hi, bin_lo, 0*30]. Total 282624 bytes.
#define WS_WINT 0
#define WS_CBX  18432
#define WS_WOX  116736

__device__ __forceinline__ u16 f2b(float f) {   // RNE float->bf16 bits
  unsigned u = __float_as_uint(f);
  return (u16)((u + 0x7FFFu + ((u >> 16) & 1u)) >> 16);
}
__device__ __forceinline__ float b2f(u16 v) {
  return __uint_as_float(((unsigned)v) << 16);
}
__device__ __forceinline__ f32x4 mfma16(u16x8 a, u16x8 b, f32x4 c) {
  return __builtin_amdgcn_mfma_f32_16x16x32_bf16(
      __builtin_bit_cast(bf16x8, a), __builtin_bit_cast(bf16x8, b), c, 0, 0, 0);
}
// async 16B/lane global->LDS DMA; LDS dst = uniform base + lane*16 (HW rule)
__device__ __forceinline__ void dma16(const u16* g, u16* l) {
  __builtin_amdgcn_global_load_lds(
      (const __attribute__((address_space(1))) unsigned int*)g,
      (__attribute__((address_space(3))) unsigned int*)l, 16, 0, 0);
}

__global__ void nsvq_prep(const float* __restrict__ cb, const float* __restrict__ Win,
                          const float* __restrict__ bin, const float* __restrict__ Wout,
                          const float* __restrict__ bout, u16* __restrict__ wsu) {
  const int g = blockIdx.x * 256 + threadIdx.x;   // 32 blocks -> 8192 threads
  u16* WinT = wsu + WS_WINT;
  u16* CbX  = wsu + WS_CBX;
  u16* WoX  = wsu + WS_WOX;
  for (int i = g; i < 16384; i += 8192) {          // WinT main: Win[c][d] -> [d][c]
    int c = i >> 6, d = i & 63;
    WinT[d * 288 + c] = f2b(Win[i]);
  }
  if (g < 2048) {                                  // WinT bias cols 256..287
    int d = g >> 5, j = g & 31; u16 v = 0;
    float bv = bin[d]; u16 h = f2b(bv);
    if (j == 0) v = h; else if (j == 1) v = f2b(bv - b2f(h));
    WinT[d * 288 + 256 + j] = v;
  }
  if (g < 1024) {                                  // CbX row
    const float4* cr = (const float4*)(cb + (size_t)g * 64);
    float vb[64]; float cn = 0.f;
    #pragma unroll
    for (int q = 0; q < 16; ++q) {
      float4 v = cr[q];
      vb[q*4] = v.x; vb[q*4+1] = v.y; vb[q*4+2] = v.z; vb[q*4+3] = v.w;
      cn = fmaf(v.x, v.x, fmaf(v.y, v.y, fmaf(v.z, v.z, fmaf(v.w, v.w, cn))));
    }
    u16* row = CbX + g * 96;
    #pragma unroll
    for (int d = 0; d < 64; ++d) row[d] = f2b(-2.f * vb[d]);
    u16 h = f2b(cn);
    row[64] = h; row[65] = f2b(cn - b2f(h));
    for (int j = 66; j < 96; ++j) row[j] = 0;
  }
  for (int i = g; i < 16384; i += 8192) {          // WoX main: Wout[d][c] -> [c][d]
    int d = i >> 8, c = i & 255;
    WoX[c * 96 + d] = f2b(Wout[i]);
  }
  {                                                // WoX bias cols 64..95 (g<8192 = 256*32)
    int c = g >> 5, j = g & 31; u16 v = 0;
    float bv = bout[c]; u16 h = f2b(bv);
    if (j == 0) v = h; else if (j == 1) v = f2b(bv - b2f(h));
    WoX[c * 96 + 64 + j] = v;
  }
}

// Block = 128 tokens, 512 threads (8 waves). Wave w owns tokens [w*16, w*16+16).
__global__ __launch_bounds__(512, 2) void nsvq_main(
    const float* __restrict__ in, const float* __restrict__ rnd,
    const u16* __restrict__ wsu, float* __restrict__ out) {
  __shared__ u16 buf[24576];        // 48 KB: WinT / CbX chunk / WoX (phased)
  __shared__ u16 InT[128 * 256];    // 64 KB, [t][c] bf16, 16B-block XOR swizzle
  __shared__ u16 Xt[128 * 64];      // 16 KB, [t][d] bf16, swizzled
  __shared__ float mnp[8][128];     // per-wave code-slice mins

  const int tid = threadIdx.x;
  const int lane = tid & 63;
  const int w = tid >> 6;                      // 0..7
  const int quad = lane >> 4, col = lane & 15;
  const int b  = blockIdx.x >> 4;              // 256 blocks
  const int t0 = (blockIdx.x & 15) << 7;
  const int myt = w * 16 + col;                // own token row in block

  // ---- stage InT (fp32 -> bf16, transpose, packed b128 writes) ----
  {
    const int t = tid & 127, cg = tid >> 7;
    const float* ib = in + (size_t)b * DIMc * Tt + t0 + t;
    #pragma unroll
    for (int it = 0; it < 8; ++it) {
      int c0 = cg * 8 + it * 32;
      u16x8 pk;
      #pragma unroll
      for (int j = 0; j < 8; ++j) pk[j] = f2b(ib[(size_t)(c0 + j) * Tt]);
      *(u16x8*)(InT + t * 256 + ((((c0 >> 3)) ^ (t & 7)) << 3)) = pk;
    }
  }
  // ---- DMA WinT -> buf (36 KB = 36 instrs) ----
  #pragma unroll
  for (int ii = 0; ii < 5; ++ii) {
    int i = w + 8 * ii;
    if (i < 36) dma16(wsu + WS_WINT + i * 512 + lane * 8, buf + i * 512);
  }
  // ---- rr2 of own token (full-wave reduce, keep via lane select) ----
  float rr2v = 0.f;
  const float* rb = rnd + ((size_t)b * Tt + t0) * Dd;
  #pragma unroll
  for (int tt = 0; tt < 16; ++tt) {
    float v = rb[(size_t)(w * 16 + tt) * Dd + lane];
    float s = v * v;
    s += __shfl_xor(s, 1);  s += __shfl_xor(s, 2);  s += __shfl_xor(s, 4);
    s += __shfl_xor(s, 8);  s += __shfl_xor(s, 16); s += __shfl_xor(s, 32);
    if (col == tt) rr2v = s;
  }
  __syncthreads();   // InT + WinT ready

  // ---- encode: X^T = WinT · InT + bin ; own 16 tokens; K=256(+32 bias) ----
  u16x8 Bc1 = {0, 0, 0, 0, 0, 0, 0, 0};
  if (quad == 0) { Bc1[0] = 0x3F80; Bc1[1] = 0x3F80; }   // bf16 1.0 pair
  f32x4 acc[4];
  {
    u16x8 Bf[8];
    #pragma unroll
    for (int kt = 0; kt < 8; ++kt)
      Bf[kt] = *(const u16x8*)(InT + myt * 256 + (((kt * 4 + quad) ^ (myt & 7)) << 3));
    #pragma unroll
    for (int mt = 0; mt < 4; ++mt) {
      f32x4 a = {0.f, 0.f, 0.f, 0.f};
      #pragma unroll
      for (int kt = 0; kt < 8; ++kt) {
        u16x8 A = *(const u16x8*)(buf + (mt * 16 + col) * 288 + kt * 32 + quad * 8);
        a = mfma16(A, Bf[kt], a);
      }
      u16x8 A8 = *(const u16x8*)(buf + (mt * 16 + col) * 288 + 256 + quad * 8);
      acc[mt] = mfma16(A8, Bc1, a);
    }
  }
  float x2v = 0.f;
  #pragma unroll
  for (int mt = 0; mt < 4; ++mt) {
    u16x4 pk;
    #pragma unroll
    for (int r = 0; r < 4; ++r) { x2v = fmaf(acc[mt][r], acc[mt][r], x2v); pk[r] = f2b(acc[mt][r]); }
    int bk = mt * 2 + (quad >> 1);
    *(u16x4*)(Xt + myt * 64 + ((bk ^ (myt & 7)) << 3) + (quad & 1) * 4) = pk;
  }
  x2v += __shfl_xor(x2v, 16);
  x2v += __shfl_xor(x2v, 32);
  __syncthreads();   // Xt complete (cross-wave reads next); buf free

  // ---- distances: wave w scans codes slice; B = all 8 n-tiles (reg cache) ----
  u16x8 Xa[8], Xb[8];
  #pragma unroll
  for (int nt = 0; nt < 8; ++nt) {
    int tr = nt * 16 + col;
    Xa[nt] = *(const u16x8*)(Xt + tr * 64 + ((quad ^ (tr & 7)) << 3));
    Xb[nt] = *(const u16x8*)(Xt + tr * 64 + (((4 + quad) ^ (tr & 7)) << 3));
  }
  float minv[8];
  #pragma unroll
  for (int i = 0; i < 8; ++i) minv[i] = 3.4e38f;
  for (int ch = 0; ch < 4; ++ch) {
    if (ch) __syncthreads();                  // prev chunk reads done
    #pragma unroll
    for (int ii = 0; ii < 6; ++ii) {          // 48 KB chunk = 48 instrs
      int i = w + 8 * ii;
      dma16(wsu + WS_CBX + ch * 24576 + i * 512 + lane * 8, buf + i * 512);
    }
    __syncthreads();                          // chunk ready
    #pragma unroll
    for (int ms = 0; ms < 2; ++ms) {          // my 2 m-tiles = 32 codes
      const u16* ar = buf + (w * 32 + ms * 16 + col) * 96;
      u16x8 A0 = *(const u16x8*)(ar + quad * 8);
      u16x8 A1 = *(const u16x8*)(ar + 32 + quad * 8);
      u16x8 A2 = *(const u16x8*)(ar + 64 + quad * 8);  // cn_hi/lo live here
      #pragma unroll
      for (int nt = 0; nt < 8; ++nt) {
        f32x4 a = {0.f, 0.f, 0.f, 0.f};
        a = mfma16(A0, Xa[nt], a);
        a = mfma16(A1, Xb[nt], a);
        a = mfma16(A2, Bc1, a);               // += cnorm
        #pragma unroll
        for (int r = 0; r < 4; ++r) minv[nt] = fminf(minv[nt], a[r]);
      }
    }
  }
  #pragma unroll
  for (int nt = 0; nt < 8; ++nt) {
    float m = minv[nt];
    m = fminf(m, __shfl_xor(m, 16));
    m = fminf(m, __shfl_xor(m, 32));
    mnp[w][nt * 16 + col] = m;                // all quads write same value
  }
  __syncthreads();   // mnp ready; buf (CbX) free

  // ---- DMA WoX; meanwhile compute sc and q-update (Xt own rows) ----
  #pragma unroll
  for (int ii = 0; ii < 6; ++ii) {
    int i = w + 8 * ii;
    dma16(wsu + WS_WOX + i * 512 + lane * 8, buf + i * 512);
  }
  float mv = 3.4e38f;
  #pragma unroll
  for (int j = 0; j < 8; ++j) mv = fminf(mv, mnp[j][myt]);
  float r2  = fmaxf(x2v + mv, 0.f);                    // ||x - hard||^2
  float scv = sqrtf(r2) / (sqrtf(rr2v) + 1e-12f);
  #pragma unroll
  for (int tt = 0; tt < 16; ++tt) {                    // q = x + sc*rnd, lane = d
    float s = __shfl(scv, tt);
    float rv = rb[(size_t)(w * 16 + tt) * Dd + lane];
    int tr = w * 16 + tt;
    int idx = tr * 64 + (((lane >> 3) ^ (tr & 7)) << 3) + (lane & 7);
    Xt[idx] = f2b(fmaf(s, rv, b2f(Xt[idx])));
  }
  __syncthreads();   // WoX ready

  // ---- decode: out = WoX · q + bout ; own 16 tokens, M=256 ----
  u16x8 Q0 = *(const u16x8*)(Xt + myt * 64 + ((quad ^ (myt & 7)) << 3));
  u16x8 Q1 = *(const u16x8*)(Xt + myt * 64 + (((4 + quad) ^ (myt & 7)) << 3));
  float* ob0 = out + (size_t)b * DIMc * Tt + t0 + myt;
  #pragma unroll
  for (int mt = 0; mt < 16; ++mt) {
    const u16* ar = buf + (mt * 16 + col) * 96;
    u16x8 A0 = *(const u16x8*)(ar + quad * 8);
    u16x8 A1 = *(const u16x8*)(ar + 32 + quad * 8);
    u16x8 A2 = *(const u16x8*)(ar + 64 + quad * 8);    // bout_hi/lo
    f32x4 a = {0.f, 0.f, 0.f, 0.f};
    a = mfma16(A0, Q0, a);
    a = mfma16(A1, Q1, a);
    a = mfma16(A2, Bc1, a);
    float* ob = ob0 + (size_t)(mt * 16 + quad * 4) * Tt;
    #pragma unroll
    for (int r = 0; r < 4; ++r) ob[(size_t)r * Tt] = a[r];
  }
}

extern "C" void kernel_launch(void* const* d_in, const int* in_sizes, int n_in,
                              void* d_out, int out_size, void* d_ws, size_t ws_size,
                              hipStream_t stream) {
  const float *in = nullptr, *cb = nullptr, *rnd = nullptr, *bin = nullptr, *bout = nullptr;
  const float* w16[2] = {nullptr, nullptr}; int nw = 0;
  for (int i = 0; i < n_in; ++i) {
    switch (in_sizes[i]) {
      case 8388608: in  = (const float*)d_in[i]; break;
      case 65536:   cb  = (const float*)d_in[i]; break;
      case 2097152: rnd = (const float*)d_in[i]; break;
      case 64:      bin = (const float*)d_in[i]; break;
      case 256:     bout= (const float*)d_in[i]; break;
      case 16384:   if (nw < 2) w16[nw++] = (const float*)d_in[i]; break;
      default: break;
    }
  }
  if (!in)  in  = (const float*)d_in[0];
  if (!cb)  cb  = (const float*)d_in[1];
  if (nw < 2) { w16[0] = (const float*)d_in[2]; w16[1] = (const float*)d_in[4]; }
  if (!bin) bin = (const float*)d_in[3];
  if (!bout) bout = (const float*)d_in[5];
  if (!rnd) rnd = (const float*)d_in[6];

  u16* wsu = (u16*)d_ws;
  float* outp = (float*)d_out;

  nsvq_prep<<<32, 256, 0, stream>>>(cb, w16[0], bin, w16[1], bout, wsu);
  nsvq_main<<<256, 512, 0, stream>>>(in, rnd, wsu, outp);
}